// Round 7
// baseline (437.377 us; speedup 1.0000x reference)
//
#include <hip/hip_runtime.h>

#define N_TOK 4096
#define DIM   1024
#define NE    16
#define NF    512
#define TOPK  4
#define CAP   4096
#define NPAIR (N_TOK * TOPK)
#define MAXTILES 144   // sum ceil(cnt/128) <= 128 + 16
#define RP_ROUTER 1024
#define RP_PREP_GU 4096
#define RP_PREP_D  2048

typedef _Float16 v8h __attribute__((ext_vector_type(8)));
typedef float    v4f __attribute__((ext_vector_type(4)));

// ------------------------------------------------- weight prep tile (256t) ---
// [E][R][C] f32 -> B^T tiled f16 image out[e][cb][kt][RI][32]
__device__ __forceinline__ void prep_tile256(
    const float* __restrict__ src, unsigned short* __restrict__ dst,
    int R, int C, int RIL, int e, int cbl, int rbl, float (*tile)[65])
{
    int c0 = cbl * 64, r0 = rbl * 64;
    const float* s = src + (size_t)e * R * C;
    int t = threadIdx.x;
    int tr = t >> 4, tc = (t & 15) * 4;
#pragma unroll
    for (int i = 0; i < 4; i++) {
        int row = i * 16 + tr;
        float4 v = *(const float4*)(s + (size_t)(r0 + row) * C + c0 + tc);
        tile[row][tc + 0] = v.x; tile[row][tc + 1] = v.y;
        tile[row][tc + 2] = v.z; tile[row][tc + 3] = v.w;
    }
    __syncthreads();
    int ktPerE = R >> 5;
    int cbPerE = C >> RIL;
    int imgSz  = (1 << RIL) * 32;
#pragma unroll
    for (int i = 0; i < 4; i++) {
        int nr = i * 16 + tr;
        int orow = c0 + nr;
        int k0 = r0 + tc;
        int cb = orow >> RIL;
        int r  = orow & ((1 << RIL) - 1);
        int kt = k0 >> 5;
        size_t off = ((size_t)(e * cbPerE + cb) * ktPerE + kt) * imgSz
                   + r * 32 + (k0 & 31);
        union { unsigned short u[4]; uint2 v; } p;
#pragma unroll
        for (int j = 0; j < 4; j++)
            p.u[j] = __builtin_bit_cast(unsigned short, (_Float16)tile[tc + j][nr]);
        *(uint2*)(dst + off) = p.v;
    }
}

// ---------------- fused router(+atomic bin) + prep(Wg,Wu) + prep(Wd) --------
// blocks [0,1024): router, 4 tokens/block (one per wave); lane0 does the
//   binning directly via atomicAdd on cnt[e] (order-free: every pair's result
//   is independent of its slot; padding rows are masked on store).
// blocks [1024,5120): prep of Wg (z<16) / Wu (z>=16), e = z&15
// blocks [5120,7168): prep of Wd
__global__ __launch_bounds__(256) void router_prep_kernel(
    const float* __restrict__ x, const float* __restrict__ Wr,
    const float* __restrict__ Wg, const float* __restrict__ Wu,
    const float* __restrict__ Wd,
    float* __restrict__ tokW,
    unsigned short* __restrict__ xb,
    unsigned short* __restrict__ Wg_t, unsigned short* __restrict__ Wu_t,
    unsigned short* __restrict__ Wd_t,
    int* __restrict__ cnt, int* __restrict__ bpair)
{
    __shared__ __align__(16) float tile[64][65];
    int bid = blockIdx.x;
    if (bid >= RP_ROUTER + RP_PREP_GU) {
        int pid = bid - (RP_ROUTER + RP_PREP_GU);   // [0,2048)
        int e = pid >> 7;
        int bx = pid & 127;
        int cbl = bx & 15, rbl = bx >> 4;
        prep_tile256(Wd, Wd_t, NF, DIM, 7, e, cbl, rbl, tile);
        return;
    }
    if (bid >= RP_ROUTER) {
        int pid = bid - RP_ROUTER;
        int z = pid >> 7;                 // [0,32)
        int which = z >> 4, e = z & 15;
        int bx = pid & 127;
        int cbl = bx & 7, rbl = bx >> 3;
        prep_tile256(which ? Wu : Wg, which ? Wu_t : Wg_t,
                     DIM, NF, 6, e, cbl, rbl, tile);
        return;
    }
    int tid = threadIdx.x;
    int w = tid >> 6, l = tid & 63;
    int t = bid * 4 + w;

    double z[NE];
#pragma unroll
    for (int e = 0; e < NE; e++) z[e] = 0.0;
    const float* xrow = x + (size_t)t * DIM;
#pragma unroll
    for (int i = 0; i < 16; i++) {
        int d = i * 64 + l;
        double xv = (double)xrow[d];
        const float4* wr = (const float4*)(Wr + d * NE);
        float4 w0 = wr[0], w1 = wr[1], w2 = wr[2], w3 = wr[3];
        z[0]  += xv * w0.x; z[1]  += xv * w0.y; z[2]  += xv * w0.z; z[3]  += xv * w0.w;
        z[4]  += xv * w1.x; z[5]  += xv * w1.y; z[6]  += xv * w1.z; z[7]  += xv * w1.w;
        z[8]  += xv * w2.x; z[9]  += xv * w2.y; z[10] += xv * w2.z; z[11] += xv * w2.w;
        z[12] += xv * w3.x; z[13] += xv * w3.y; z[14] += xv * w3.z; z[15] += xv * w3.w;
    }
    // fused cast: two 8-elem chunks per lane (row is L1-hot)
    const float4* xv4 = (const float4*)xrow;
#pragma unroll
    for (int h2 = 0; h2 < 2; h2++) {
        int base = h2 * 512 + l * 8;
        float4 a = xv4[h2 * 128 + l * 2];
        float4 b = xv4[h2 * 128 + l * 2 + 1];
        union { unsigned short u[8]; uint4 v; } p;
        p.u[0] = __builtin_bit_cast(unsigned short, (_Float16)a.x);
        p.u[1] = __builtin_bit_cast(unsigned short, (_Float16)a.y);
        p.u[2] = __builtin_bit_cast(unsigned short, (_Float16)a.z);
        p.u[3] = __builtin_bit_cast(unsigned short, (_Float16)a.w);
        p.u[4] = __builtin_bit_cast(unsigned short, (_Float16)b.x);
        p.u[5] = __builtin_bit_cast(unsigned short, (_Float16)b.y);
        p.u[6] = __builtin_bit_cast(unsigned short, (_Float16)b.z);
        p.u[7] = __builtin_bit_cast(unsigned short, (_Float16)b.w);
        *(uint4*)(xb + (size_t)t * DIM + base) = p.v;
    }
#pragma unroll
    for (int e = 0; e < NE; e++) {
#pragma unroll
        for (int m = 1; m < 64; m <<= 1) z[e] += __shfl_xor(z[e], m, 64);
    }
    if (l == 0) {
        bool taken[NE];
#pragma unroll
        for (int e = 0; e < NE; e++) taken[e] = false;
        int idx[TOPK]; double sel[TOPK];
        for (int k = 0; k < TOPK; k++) {
            int bi = 0; double bv = -1.0e300;
            for (int e = 0; e < NE; e++)
                if (!taken[e] && z[e] > bv) { bv = z[e]; bi = e; }
            taken[bi] = true; idx[k] = bi; sel[k] = bv;
        }
        double m = sel[0];
        double ex[TOPK]; double s = 0.0;
        for (int k = 0; k < TOPK; k++) { ex[k] = exp(sel[k] - m); s += ex[k]; }
        for (int k = 0; k < TOPK; k++) {
            tokW[t * TOPK + k] = (float)(ex[k] / s);
            int e = idx[k];
            int slot = atomicAdd(&cnt[e], 1);      // device-scope, order-free
            bpair[e * CAP + slot] = t * TOPK + k;
        }
    }
}

// LDS chunk swizzle (R5-proven: 0 measured conflicts). XOR is an involution:
// same permutation is applied on the global SOURCE (staging) and on the READ.
__device__ __forceinline__ int ldsw(int row, int chunk) {
    return row * 32 + (chunk ^ ((row >> 1) & 3)) * 8;
}

// direct global->LDS, 16B/lane; LDS dest = wave-uniform base + lane*16 (linear)
__device__ __forceinline__ void gload16(const unsigned short* g, unsigned short* l) {
    __builtin_amdgcn_global_load_lds(
        (const __attribute__((address_space(1))) void*)g,
        (__attribute__((address_space(3))) void*)l, 16, 0, 0);
}

// per-block tile lookup from cnt[]
__device__ __forceinline__ bool find_tile(const int* __restrict__ cnt,
                                          int ti, int& e, int& mt, int& tbase) {
    int rt = 0;
#pragma unroll 1
    for (int ee = 0; ee < NE; ee++) {
        int nt = (cnt[ee] + 127) >> 7;
        if (ti < rt + nt) { e = ee; mt = ti - rt; tbase = rt; return true; }
        rt += nt;
    }
    return false;
}

// --------------------------------------------------------- gate/up + silu ----
// Round-2-proven body (best total 271.4): 128x128 tile (64 G + 64 U cols),
// BK=32, gload_lds double-buffer, one __syncthreads per K-step. Pure GEMM
// dispatch (prep removed). 33 KB LDS -> 4 blocks/CU.
__global__ __launch_bounds__(256) void ffn_gate_up_kernel(
    const unsigned short* __restrict__ xb,
    const unsigned short* __restrict__ Wg_t,   // [e][fb8][kt32][64][32]
    const unsigned short* __restrict__ Wu_t,
    const int* __restrict__ cnt,
    const int* __restrict__ bpair,
    unsigned short* __restrict__ h_t)          // [tile][f16][128][32]
{
    __shared__ __align__(16) unsigned short sX[2 * 128 * 32];
    __shared__ __align__(16) unsigned short sG[2 * 64 * 32];
    __shared__ __align__(16) unsigned short sU[2 * 64 * 32];
    __shared__ int sTok[128];

    int fb = blockIdx.x, ti = blockIdx.y;
    int e, mt, tbase;
    if (!find_tile(cnt, ti, e, mt, tbase)) return;
    int count = cnt[e];

    int tid = threadIdx.x, lane = tid & 63, w = tid >> 6;
    if (tid < 128) {
        int pos = mt * 128 + tid;
        sTok[tid] = bpair[e * CAP + min(pos, count - 1)] >> 2;
    }
    __syncthreads();

    // staging geometry: wave w covers rows [w*16, w*16+16) per call.
    int srow0 = w * 16 + (lane >> 2);          // [0,64)
    int srow1 = srow0 + 64;                    // [64,128)
    int spos  = lane & 3;
    int cx0 = spos ^ ((srow0 >> 1) & 3);
    int cx1 = spos ^ ((srow1 >> 1) & 3);
    const unsigned short* gX0 = xb + (size_t)sTok[srow0] * DIM + cx0 * 8;
    const unsigned short* gX1 = xb + (size_t)sTok[srow1] * DIM + cx1 * 8;
    const unsigned short* gG  = Wg_t + ((size_t)(e * 8 + fb) * 32) * 2048 + srow0 * 32 + cx0 * 8;
    const unsigned short* gU  = Wu_t + ((size_t)(e * 8 + fb) * 32) * 2048 + srow0 * 32 + cx0 * 8;
    unsigned short* dX0 = sX + (size_t)(w * 16) * 32;        // + buf*4096
    unsigned short* dX1 = sX + (size_t)(64 + w * 16) * 32;
    unsigned short* dG  = sG + (size_t)(w * 16) * 32;        // + buf*2048
    unsigned short* dU  = sU + (size_t)(w * 16) * 32;

    int row = lane & 15, q = lane >> 4;
    int rw = w & 1, cw = w >> 1;
    int aoff[4], goff[2];
#pragma unroll
    for (int mi = 0; mi < 4; mi++) aoff[mi] = ldsw(rw * 64 + mi * 16 + row, q);
#pragma unroll
    for (int ni = 0; ni < 2; ni++) goff[ni] = ldsw(cw * 32 + ni * 16 + row, q);

    v4f accG[4][2], accU[4][2];
    v4f zero = {0.f, 0.f, 0.f, 0.f};
#pragma unroll
    for (int mi = 0; mi < 4; mi++)
#pragma unroll
        for (int ni = 0; ni < 2; ni++) { accG[mi][ni] = zero; accU[mi][ni] = zero; }

#define STAGE_GU(b, kt) do {                                   \
        gload16(gX0 + (kt) * 32, dX0 + (b) * 4096);            \
        gload16(gX1 + (kt) * 32, dX1 + (b) * 4096);            \
        gload16(gG + (size_t)(kt) * 2048, dG + (b) * 2048);    \
        gload16(gU + (size_t)(kt) * 2048, dU + (b) * 2048);    \
    } while (0)

    STAGE_GU(0, 0);
    __syncthreads();   // vmcnt(0) drain: buf0 ready

#pragma unroll 1
    for (int kt = 0; kt < 32; kt++) {
        int buf = kt & 1;
        if (kt < 31) STAGE_GU(buf ^ 1, kt + 1);   // in flight under compute
        const unsigned short* bX = sX + buf * 4096;
        const unsigned short* bGp = sG + buf * 2048;
        const unsigned short* bUp = sU + buf * 2048;
        v8h a[4], bg[2], bu[2];
#pragma unroll
        for (int mi = 0; mi < 4; mi++) a[mi] = *(const v8h*)&bX[aoff[mi]];
#pragma unroll
        for (int ni = 0; ni < 2; ni++) {
            bg[ni] = *(const v8h*)&bGp[goff[ni]];
            bu[ni] = *(const v8h*)&bUp[goff[ni]];
        }
#pragma unroll
        for (int mi = 0; mi < 4; mi++)
#pragma unroll
            for (int ni = 0; ni < 2; ni++) {
                accG[mi][ni] = __builtin_amdgcn_mfma_f32_16x16x32_f16(a[mi], bg[ni], accG[mi][ni], 0, 0, 0);
                accU[mi][ni] = __builtin_amdgcn_mfma_f32_16x16x32_f16(a[mi], bu[ni], accU[mi][ni], 0, 0, 0);
            }
        __syncthreads();  // drains vmcnt (next buf landed) + all reads of buf done
    }
#undef STAGE_GU

    size_t himg = (size_t)(tbase + mt) * 16;
#pragma unroll
    for (int mi = 0; mi < 4; mi++)
#pragma unroll
        for (int ni = 0; ni < 2; ni++) {
            int f = fb * 64 + cw * 32 + ni * 16 + row;    // C/D: col = lane&15
#pragma unroll
            for (int i = 0; i < 4; i++) {
                int rl = rw * 64 + mi * 16 + q * 4 + i;   // C/D: row = quad*4+reg
                int pos = mt * 128 + rl;
                if (pos < count) {
                    float gv = accG[mi][ni][i];
                    float uv = accU[mi][ni][i];
                    float hv = gv * uv / (1.0f + __expf(-gv));
                    size_t off = (himg + (f >> 5)) * 4096 + rl * 32 + (f & 31);
                    h_t[off] = __builtin_bit_cast(unsigned short, (_Float16)hv);
                }
            }
        }
}

// ----------------------------------------------------------- down (no atomics)
__global__ __launch_bounds__(256) void ffn_down_kernel(
    const unsigned short* __restrict__ h_t,
    const unsigned short* __restrict__ Wd_t,   // [e][db8][kt16][128][32]
    const int* __restrict__ cnt,
    const int* __restrict__ bpair,
    unsigned short* __restrict__ part)         // [NPAIR][DIM] f16
{
    int ti = blockIdx.x, db = blockIdx.y;
    int e, mt, tbase;
    if (!find_tile(cnt, ti, e, mt, tbase)) return;
    int count = cnt[e];

    __shared__ __align__(16) unsigned short sH[2 * 128 * 32];
    __shared__ __align__(16) unsigned short sW[2 * 128 * 32];
    __shared__ int sPair[128];

    int tid = threadIdx.x, lane = tid & 63, w = tid >> 6;
    if (tid < 128) {
        int pos = mt * 128 + tid;
        sPair[tid] = bpair[e * CAP + min(pos, count - 1)];
    }
    __syncthreads();

    int srow0 = w * 16 + (lane >> 2);
    int srow1 = srow0 + 64;
    int spos  = lane & 3;
    int c0 = spos ^ ((srow0 >> 1) & 3);
    int c1 = spos ^ ((srow1 >> 1) & 3);
    const unsigned short* hbase = h_t + ((size_t)(tbase + mt) * 16) * 4096;
    const unsigned short* wbase = Wd_t + ((size_t)(e * 8 + db) * 16) * 4096;
    const unsigned short* gH0 = hbase + srow0 * 32 + c0 * 8;
    const unsigned short* gH1 = hbase + srow1 * 32 + c1 * 8;
    const unsigned short* gW0 = wbase + srow0 * 32 + c0 * 8;
    const unsigned short* gW1 = wbase + srow1 * 32 + c1 * 8;
    unsigned short* dH0 = sH + (size_t)(w * 16) * 32;
    unsigned short* dH1 = sH + (size_t)(64 + w * 16) * 32;
    unsigned short* dW0 = sW + (size_t)(w * 16) * 32;
    unsigned short* dW1 = sW + (size_t)(64 + w * 16) * 32;

    int row = lane & 15, q = lane >> 4;
    int rw = w & 1, cw = w >> 1;
    int aoff[4], boff[4];
#pragma unroll
    for (int mi = 0; mi < 4; mi++) aoff[mi] = ldsw(rw * 64 + mi * 16 + row, q);
#pragma unroll
    for (int ni = 0; ni < 4; ni++) boff[ni] = ldsw(cw * 64 + ni * 16 + row, q);

    v4f acc[4][4];
    v4f zero = {0.f, 0.f, 0.f, 0.f};
#pragma unroll
    for (int mi = 0; mi < 4; mi++)
#pragma unroll
        for (int ni = 0; ni < 4; ni++) acc[mi][ni] = zero;

#define STAGE_D(b, kt) do {                                         \
        gload16(gH0 + (size_t)(kt) * 4096, dH0 + (b) * 4096);       \
        gload16(gH1 + (size_t)(kt) * 4096, dH1 + (b) * 4096);       \
        gload16(gW0 + (size_t)(kt) * 4096, dW0 + (b) * 4096);       \
        gload16(gW1 + (size_t)(kt) * 4096, dW1 + (b) * 4096);       \
    } while (0)

    STAGE_D(0, 0);
    __syncthreads();

#pragma unroll 1
    for (int kt = 0; kt < 16; kt++) {
        int buf = kt & 1;
        if (kt < 15) STAGE_D(buf ^ 1, kt + 1);
        const unsigned short* bH = sH + buf * 4096;
        const unsigned short* bW = sW + buf * 4096;
        v8h a[4], b[4];
#pragma unroll
        for (int mi = 0; mi < 4; mi++) a[mi] = *(const v8h*)&bH[aoff[mi]];
#pragma unroll
        for (int ni = 0; ni < 4; ni++) b[ni] = *(const v8h*)&bW[boff[ni]];
#pragma unroll
        for (int mi = 0; mi < 4; mi++)
#pragma unroll
            for (int ni = 0; ni < 4; ni++)
                acc[mi][ni] = __builtin_amdgcn_mfma_f32_16x16x32_f16(a[mi], b[ni], acc[mi][ni], 0, 0, 0);
        __syncthreads();
    }
#undef STAGE_D

#pragma unroll
    for (int mi = 0; mi < 4; mi++)
#pragma unroll
        for (int ni = 0; ni < 4; ni++) {
            int col = db * 128 + cw * 64 + ni * 16 + row;
#pragma unroll
            for (int i = 0; i < 4; i++) {
                int rl = rw * 64 + mi * 16 + q * 4 + i;
                int pos = mt * 128 + rl;
                if (pos < count) {
                    int p = sPair[rl];
                    part[(size_t)p * DIM + col] =
                        __builtin_bit_cast(unsigned short, (_Float16)acc[mi][ni][i]);
                }
            }
        }
}

// ---------------------------------------------------------------- combine ----
__global__ __launch_bounds__(256) void combine_kernel(
    const unsigned short* __restrict__ part, const float* __restrict__ tokW,
    float* __restrict__ out)
{
    int gid = blockIdx.x * 256 + threadIdx.x;
    int t = gid >> 8;
    int c = (gid & 255) * 4;
    float4 r = {0.f, 0.f, 0.f, 0.f};
#pragma unroll
    for (int k = 0; k < TOPK; k++) {
        float wk = tokW[t * TOPK + k];
        union { uint2 u; _Float16 h[4]; } cv;
        cv.u = *(const uint2*)(part + ((size_t)(t * TOPK + k)) * DIM + c);
        r.x += wk * (float)cv.h[0];
        r.y += wk * (float)cv.h[1];
        r.z += wk * (float)cv.h[2];
        r.w += wk * (float)cv.h[3];
    }
    *(float4*)(out + (size_t)t * DIM + c) = r;
}

// ------------------------------------------------------------------- host ----
extern "C" void kernel_launch(void* const* d_in, const int* in_sizes, int n_in,
                              void* d_out, int out_size, void* d_ws, size_t ws_size,
                              hipStream_t stream)
{
    const float* x  = (const float*)d_in[0];
    const float* Wr = (const float*)d_in[1];
    const float* Wg = (const float*)d_in[2];
    const float* Wu = (const float*)d_in[3];
    const float* Wd = (const float*)d_in[4];
    float* out = (float*)d_out;
    char* ws = (char*)d_ws;

    size_t off = 0;
    float* tokW = (float*)(ws + off); off += (size_t)NPAIR * 4;
    int* cnt    = (int*)(ws + off);   off += 256;
    int* bpair  = (int*)(ws + off);   off += (size_t)NE * CAP * 4;
    unsigned short* xb   = (unsigned short*)(ws + off); off += (size_t)N_TOK * DIM * 2;
    unsigned short* Wg_t = (unsigned short*)(ws + off); off += (size_t)NE * DIM * NF * 2;
    unsigned short* Wu_t = (unsigned short*)(ws + off); off += (size_t)NE * DIM * NF * 2;
    unsigned short* Wd_t = (unsigned short*)(ws + off); off += (size_t)NE * DIM * NF * 2;
    unsigned short* h_t  = (unsigned short*)(ws + off); off += (size_t)MAXTILES * 16 * 4096 * 2;
    unsigned short* part = (unsigned short*)(ws + off); off += (size_t)NPAIR * DIM * 2;

    hipMemsetAsync(cnt, 0, 256, stream);   // atomic-bin counters

    // router+bin (1024) + prep Wg/Wu (4096) + prep Wd (2048), concurrent
    router_prep_kernel<<<RP_ROUTER + RP_PREP_GU + RP_PREP_D, 256, 0, stream>>>(
        x, Wr, Wg, Wu, Wd, tokW, xb, Wg_t, Wu_t, Wd_t, cnt, bpair);
    // pure gate_up GEMM
    ffn_gate_up_kernel<<<dim3(8, MAXTILES), 256, 0, stream>>>(
        xb, Wg_t, Wu_t, cnt, bpair, h_t);
    ffn_down_kernel<<<dim3(MAXTILES, 8), 256, 0, stream>>>(
        h_t, Wd_t, cnt, bpair, part);
    combine_kernel<<<(N_TOK * DIM) / (256 * 4), 256, 0, stream>>>(part, tokW, out);
}

// Round 8
// 269.117 us; speedup vs baseline: 1.6252x; 1.6252x over previous
//
#include <hip/hip_runtime.h>

#define N_TOK 4096
#define DIM   1024
#define NE    16
#define NF    512
#define TOPK  4
#define CAP   4096
#define NPAIR (N_TOK * TOPK)
#define MAXTILES 144   // sum ceil(cnt/128) <= 128 + 16  (= 8 XCDs x 18)
#define GU_BLOCKS (8 * MAXTILES)   // 1152 gate_up GEMM blocks
#define DN_BLOCKS (8 * MAXTILES)   // 1152 down GEMM blocks
#define PREPD_BLOCKS (NE * 128)    // 2048 Wd prep blocks
#define RP_ROUTER 1024
#define RP_PREP   4096

typedef _Float16 v8h __attribute__((ext_vector_type(8)));
typedef float    v4f __attribute__((ext_vector_type(4)));

// ------------------------------------------------------- weight prep tile ----
// [E][R][C] f32 -> B^T tiled f16 image out[e][cb][kt][RI][32]
__device__ __forceinline__ void prep_tile(
    const float* __restrict__ src, unsigned short* __restrict__ dst,
    int R, int C, int RIL, int e, int cbl, int rbl, float (*tile)[65])
{
    int c0 = cbl * 64, r0 = rbl * 64;
    const float* s = src + (size_t)e * R * C;
    int t = threadIdx.x;
    int tr = t >> 4, tc = (t & 15) * 4;
#pragma unroll
    for (int i = 0; i < 4; i++) {
        int row = i * 16 + tr;
        float4 v = *(const float4*)(s + (size_t)(r0 + row) * C + c0 + tc);
        tile[row][tc + 0] = v.x; tile[row][tc + 1] = v.y;
        tile[row][tc + 2] = v.z; tile[row][tc + 3] = v.w;
    }
    __syncthreads();
    int ktPerE = R >> 5;
    int cbPerE = C >> RIL;
    int imgSz  = (1 << RIL) * 32;
#pragma unroll
    for (int i = 0; i < 4; i++) {
        int nr = i * 16 + tr;
        int orow = c0 + nr;
        int k0 = r0 + tc;
        int cb = orow >> RIL;
        int r  = orow & ((1 << RIL) - 1);
        int kt = k0 >> 5;
        size_t off = ((size_t)(e * cbPerE + cb) * ktPerE + kt) * imgSz
                   + r * 32 + (k0 & 31);
        union { unsigned short u[4]; uint2 v; } p;
#pragma unroll
        for (int j = 0; j < 4; j++)
            p.u[j] = __builtin_bit_cast(unsigned short, (_Float16)tile[tc + j][nr]);
        *(uint2*)(dst + off) = p.v;
    }
}

// ------------------------------------------- fused router + prep(Wg,Wu) -----
// blocks [0,1024): router, 4 tokens/block (one per wave)
// blocks [1024, 5120): prep of Wg (z<16) / Wu (z>=16), e = z&15
__global__ __launch_bounds__(256) void router_prep_kernel(
    const float* __restrict__ x, const float* __restrict__ Wr,
    const float* __restrict__ Wg, const float* __restrict__ Wu,
    int* __restrict__ tokIdx, float* __restrict__ tokW,
    unsigned short* __restrict__ xb,
    unsigned short* __restrict__ Wg_t, unsigned short* __restrict__ Wu_t)
{
    __shared__ __align__(16) float tile[64][65];
    int bid = blockIdx.x;
    if (bid >= RP_ROUTER) {
        int pid = bid - RP_ROUTER;
        int z = pid >> 7;                 // [0,32)
        int which = z >> 4, e = z & 15;
        int bx = pid & 127;
        int cbl = bx & 7, rbl = bx >> 3;
        prep_tile(which ? Wu : Wg, which ? Wu_t : Wg_t,
                  DIM, NF, 6, e, cbl, rbl, tile);
        return;
    }
    int tid = threadIdx.x;
    int w = tid >> 6, l = tid & 63;
    int t = bid * 4 + w;

    double z[NE];
#pragma unroll
    for (int e = 0; e < NE; e++) z[e] = 0.0;
    const float* xrow = x + (size_t)t * DIM;
#pragma unroll
    for (int i = 0; i < 16; i++) {
        int d = i * 64 + l;
        double xv = (double)xrow[d];
        const float4* wr = (const float4*)(Wr + d * NE);
        float4 w0 = wr[0], w1 = wr[1], w2 = wr[2], w3 = wr[3];
        z[0]  += xv * w0.x; z[1]  += xv * w0.y; z[2]  += xv * w0.z; z[3]  += xv * w0.w;
        z[4]  += xv * w1.x; z[5]  += xv * w1.y; z[6]  += xv * w1.z; z[7]  += xv * w1.w;
        z[8]  += xv * w2.x; z[9]  += xv * w2.y; z[10] += xv * w2.z; z[11] += xv * w2.w;
        z[12] += xv * w3.x; z[13] += xv * w3.y; z[14] += xv * w3.z; z[15] += xv * w3.w;
    }
    // fused cast: two 8-elem chunks per lane (row is L1-hot)
    const float4* xv4 = (const float4*)xrow;
#pragma unroll
    for (int h2 = 0; h2 < 2; h2++) {
        int base = h2 * 512 + l * 8;
        float4 a = xv4[h2 * 128 + l * 2];
        float4 b = xv4[h2 * 128 + l * 2 + 1];
        union { unsigned short u[8]; uint4 v; } p;
        p.u[0] = __builtin_bit_cast(unsigned short, (_Float16)a.x);
        p.u[1] = __builtin_bit_cast(unsigned short, (_Float16)a.y);
        p.u[2] = __builtin_bit_cast(unsigned short, (_Float16)a.z);
        p.u[3] = __builtin_bit_cast(unsigned short, (_Float16)a.w);
        p.u[4] = __builtin_bit_cast(unsigned short, (_Float16)b.x);
        p.u[5] = __builtin_bit_cast(unsigned short, (_Float16)b.y);
        p.u[6] = __builtin_bit_cast(unsigned short, (_Float16)b.z);
        p.u[7] = __builtin_bit_cast(unsigned short, (_Float16)b.w);
        *(uint4*)(xb + (size_t)t * DIM + base) = p.v;
    }
#pragma unroll
    for (int e = 0; e < NE; e++) {
#pragma unroll
        for (int m = 1; m < 64; m <<= 1) z[e] += __shfl_xor(z[e], m, 64);
    }
    if (l == 0) {
        bool taken[NE];
#pragma unroll
        for (int e = 0; e < NE; e++) taken[e] = false;
        int idx[TOPK]; double sel[TOPK];
        for (int k = 0; k < TOPK; k++) {
            int bi = 0; double bv = -1.0e300;
            for (int e = 0; e < NE; e++)
                if (!taken[e] && z[e] > bv) { bv = z[e]; bi = e; }
            taken[bi] = true; idx[k] = bi; sel[k] = bv;
        }
        double m = sel[0];
        double ex[TOPK]; double s = 0.0;
        for (int k = 0; k < TOPK; k++) { ex[k] = exp(sel[k] - m); s += ex[k]; }
        for (int k = 0; k < TOPK; k++) {
            tokIdx[t * TOPK + k] = idx[k];
            tokW[t * TOPK + k]   = (float)(ex[k] / s);
        }
    }
}

// ------------------------------------------------------------------ binning --
// 16 blocks, one per expert; ballot rank + LDS cross-wave prefix; deterministic.
__global__ __launch_bounds__(256) void bin_kernel(
    const int* __restrict__ tokIdx,
    int* __restrict__ cnt, int* __restrict__ bpair)
{
    int e = blockIdx.x;
    int tid = threadIdx.x, lane = tid & 63, wv = tid >> 6;
    __shared__ int wsum[4];
    __shared__ int sbase;
    if (tid == 0) sbase = 0;
    __syncthreads();
    unsigned long long lt = (1ULL << lane) - 1ULL;
#pragma unroll 1
    for (int c0 = 0; c0 < NPAIR; c0 += 1024) {
        int i0 = c0 + tid * 4;
        int4 v = *(const int4*)(tokIdx + i0);
        int m[4] = {v.x == e, v.y == e, v.z == e, v.w == e};
        int r[4]; int wcnt = 0;
#pragma unroll
        for (int j = 0; j < 4; j++) {
            unsigned long long bal = __ballot(m[j] != 0);
            r[j] = wcnt + __popcll(bal & lt);
            wcnt += __popcll(bal);
        }
        if (lane == 0) wsum[wv] = wcnt;
        __syncthreads();
        int woff = sbase;
        for (int k = 0; k < wv; k++) woff += wsum[k];
#pragma unroll
        for (int j = 0; j < 4; j++)
            if (m[j]) bpair[e * CAP + woff + r[j]] = i0 + j;
        __syncthreads();
        if (tid == 0) sbase += wsum[0] + wsum[1] + wsum[2] + wsum[3];
        __syncthreads();
    }
    if (tid == 0) cnt[e] = sbase;
}

// LDS chunk swizzle (R5-proven: 0 measured conflicts). XOR is an involution:
// same permutation is applied on the global SOURCE (staging) and on the READ.
__device__ __forceinline__ int ldsw(int row, int chunk) {
    return row * 32 + (chunk ^ ((row >> 1) & 3)) * 8;
}

// direct global->LDS, 16B/lane; LDS dest = wave-uniform base + lane*16 (linear)
__device__ __forceinline__ void gload16(const unsigned short* g, unsigned short* l) {
    __builtin_amdgcn_global_load_lds(
        (const __attribute__((address_space(1))) void*)g,
        (__attribute__((address_space(3))) void*)l, 16, 0, 0);
}

// per-block tile lookup from cnt[]
__device__ __forceinline__ bool find_tile(const int* __restrict__ cnt,
                                          int ti, int& e, int& mt, int& tbase) {
    int rt = 0;
#pragma unroll 1
    for (int ee = 0; ee < NE; ee++) {
        int nt = (cnt[ee] + 127) >> 7;
        if (ti < rt + nt) { e = ee; mt = ti - rt; tbase = rt; return true; }
        rt += nt;
    }
    return false;
}

// ------------------------------------- gate/up + silu, fused with prep(Wd) ---
// blocks [0,1152): GEMM 128x128 tile (64 G + 64 U cols), BK=32, gload_lds
//   double-buffer, one __syncthreads per K-step (round-2 champion body).
//   T1 XCD swizzle: xcd = bid%8 (HW round-robin); each XCD owns ti range
//   [18*xcd, 18*xcd+18) x all 8 fb -> X tiles and same-expert weight images
//   cluster in one XCD's L2 (live X set = 16 tiles x 256 KB ~ 4 MB = L2).
// blocks [1152, 1152+2048): prep of Wd (consumed by ffn_down next).
__global__ __launch_bounds__(256) void ffn_gate_up_kernel(
    const unsigned short* __restrict__ xb,
    const unsigned short* __restrict__ Wg_t,   // [e][fb8][kt32][64][32]
    const unsigned short* __restrict__ Wu_t,
    const int* __restrict__ cnt,
    const int* __restrict__ bpair,
    unsigned short* __restrict__ h_t,          // [tile][kt16][128][32]
    const float* __restrict__ Wd,
    unsigned short* __restrict__ Wd_t)
{
    __shared__ __align__(16) unsigned char smem[33536];
    unsigned short* sX = (unsigned short*)smem;              // 16384 B
    unsigned short* sG = (unsigned short*)(smem + 16384);    //  8192 B
    unsigned short* sU = (unsigned short*)(smem + 24576);    //  8192 B
    int* sTok = (int*)(smem + 32768);                        //   512 B
    float (*tile)[65] = (float (*)[65])smem;                 // 16640 B (prep)

    int bid = blockIdx.x;
    if (bid >= GU_BLOCKS) {
        int pid = bid - GU_BLOCKS;
        int e = pid >> 7;
        int bx = pid & 127;
        int cbl = bx & 15, rbl = bx >> 4;
        prep_tile(Wd, Wd_t, NF, DIM, 7, e, cbl, rbl, tile);
        return;
    }
    // XCD-aware swizzle (T1): same-ti fb-siblings and same-expert ti-runs
    // land on one XCD's L2.
    int xcd = bid & 7, q = bid >> 3;           // q in [0,144)
    int ti = xcd * 18 + (q >> 3);
    int fb = q & 7;
    int e, mt, tbase;
    if (!find_tile(cnt, ti, e, mt, tbase)) return;
    int count = cnt[e];

    int tid = threadIdx.x, lane = tid & 63, w = tid >> 6;
    if (tid < 128) {
        int pos = mt * 128 + tid;
        sTok[tid] = bpair[e * CAP + min(pos, count - 1)] >> 2;
    }
    __syncthreads();

    // staging geometry: wave w covers rows [w*16, w*16+16) per call.
    int srow0 = w * 16 + (lane >> 2);          // [0,64)
    int srow1 = srow0 + 64;                    // [64,128)
    int spos  = lane & 3;
    int cx0 = spos ^ ((srow0 >> 1) & 3);
    int cx1 = spos ^ ((srow1 >> 1) & 3);
    const unsigned short* gX0 = xb + (size_t)sTok[srow0] * DIM + cx0 * 8;
    const unsigned short* gX1 = xb + (size_t)sTok[srow1] * DIM + cx1 * 8;
    const unsigned short* gG  = Wg_t + ((size_t)(e * 8 + fb) * 32) * 2048 + srow0 * 32 + cx0 * 8;
    const unsigned short* gU  = Wu_t + ((size_t)(e * 8 + fb) * 32) * 2048 + srow0 * 32 + cx0 * 8;
    unsigned short* dX0 = sX + (size_t)(w * 16) * 32;        // + buf*4096
    unsigned short* dX1 = sX + (size_t)(64 + w * 16) * 32;
    unsigned short* dG  = sG + (size_t)(w * 16) * 32;        // + buf*2048
    unsigned short* dU  = sU + (size_t)(w * 16) * 32;

    int row = lane & 15, q2 = lane >> 4;
    int rw = w & 1, cw = w >> 1;
    int aoff[4], goff[2];
#pragma unroll
    for (int mi = 0; mi < 4; mi++) aoff[mi] = ldsw(rw * 64 + mi * 16 + row, q2);
#pragma unroll
    for (int ni = 0; ni < 2; ni++) goff[ni] = ldsw(cw * 32 + ni * 16 + row, q2);

    v4f accG[4][2], accU[4][2];
    v4f zero = {0.f, 0.f, 0.f, 0.f};
#pragma unroll
    for (int mi = 0; mi < 4; mi++)
#pragma unroll
        for (int ni = 0; ni < 2; ni++) { accG[mi][ni] = zero; accU[mi][ni] = zero; }

#define STAGE_GU(b, kt) do {                                   \
        gload16(gX0 + (kt) * 32, dX0 + (b) * 4096);            \
        gload16(gX1 + (kt) * 32, dX1 + (b) * 4096);            \
        gload16(gG + (size_t)(kt) * 2048, dG + (b) * 2048);    \
        gload16(gU + (size_t)(kt) * 2048, dU + (b) * 2048);    \
    } while (0)

    STAGE_GU(0, 0);
    __syncthreads();   // vmcnt(0) drain: buf0 ready

#pragma unroll 1
    for (int kt = 0; kt < 32; kt++) {
        int buf = kt & 1;
        if (kt < 31) STAGE_GU(buf ^ 1, kt + 1);   // in flight under compute
        const unsigned short* bX = sX + buf * 4096;
        const unsigned short* bGp = sG + buf * 2048;
        const unsigned short* bUp = sU + buf * 2048;
        v8h a[4], bg[2], bu[2];
#pragma unroll
        for (int mi = 0; mi < 4; mi++) a[mi] = *(const v8h*)&bX[aoff[mi]];
#pragma unroll
        for (int ni = 0; ni < 2; ni++) {
            bg[ni] = *(const v8h*)&bGp[goff[ni]];
            bu[ni] = *(const v8h*)&bUp[goff[ni]];
        }
#pragma unroll
        for (int mi = 0; mi < 4; mi++)
#pragma unroll
            for (int ni = 0; ni < 2; ni++) {
                accG[mi][ni] = __builtin_amdgcn_mfma_f32_16x16x32_f16(a[mi], bg[ni], accG[mi][ni], 0, 0, 0);
                accU[mi][ni] = __builtin_amdgcn_mfma_f32_16x16x32_f16(a[mi], bu[ni], accU[mi][ni], 0, 0, 0);
            }
        __syncthreads();  // drains vmcnt (next buf landed) + all reads of buf done
    }
#undef STAGE_GU

    size_t himg = (size_t)(tbase + mt) * 16;
#pragma unroll
    for (int mi = 0; mi < 4; mi++)
#pragma unroll
        for (int ni = 0; ni < 2; ni++) {
            int f = fb * 64 + cw * 32 + ni * 16 + row;    // C/D: col = lane&15
#pragma unroll
            for (int i = 0; i < 4; i++) {
                int rl = rw * 64 + mi * 16 + q2 * 4 + i;  // C/D: row = quad*4+reg
                int pos = mt * 128 + rl;
                if (pos < count) {
                    float gv = accG[mi][ni][i];
                    float uv = accU[mi][ni][i];
                    float hv = gv * uv / (1.0f + __expf(-gv));
                    size_t off = (himg + (f >> 5)) * 4096 + rl * 32 + (f & 31);
                    h_t[off] = __builtin_bit_cast(unsigned short, (_Float16)hv);
                }
            }
        }
}

// ----------------------------------------------------------- down (no atomics)
// T1 XCD swizzle: each XCD owns ti in [18*xcd, 18*xcd+18) x all 8 db ->
// h tiles and same-expert Wd images cluster per-XCD L2.
__global__ __launch_bounds__(256) void ffn_down_kernel(
    const unsigned short* __restrict__ h_t,
    const unsigned short* __restrict__ Wd_t,   // [e][db8][kt16][128][32]
    const int* __restrict__ cnt,
    const int* __restrict__ bpair,
    unsigned short* __restrict__ part)         // [NPAIR][DIM] f16
{
    int bid = blockIdx.x;
    int xcd = bid & 7, q = bid >> 3;           // q in [0,144)
    int ti = xcd * 18 + (q >> 3);
    int db = q & 7;
    int e, mt, tbase;
    if (!find_tile(cnt, ti, e, mt, tbase)) return;
    int count = cnt[e];

    __shared__ __align__(16) unsigned short sH[2 * 128 * 32];
    __shared__ __align__(16) unsigned short sW[2 * 128 * 32];
    __shared__ int sPair[128];

    int tid = threadIdx.x, lane = tid & 63, w = tid >> 6;
    if (tid < 128) {
        int pos = mt * 128 + tid;
        sPair[tid] = bpair[e * CAP + min(pos, count - 1)];
    }
    __syncthreads();

    int srow0 = w * 16 + (lane >> 2);
    int srow1 = srow0 + 64;
    int spos  = lane & 3;
    int c0 = spos ^ ((srow0 >> 1) & 3);
    int c1 = spos ^ ((srow1 >> 1) & 3);
    const unsigned short* hbase = h_t + ((size_t)(tbase + mt) * 16) * 4096;
    const unsigned short* wbase = Wd_t + ((size_t)(e * 8 + db) * 16) * 4096;
    const unsigned short* gH0 = hbase + srow0 * 32 + c0 * 8;
    const unsigned short* gH1 = hbase + srow1 * 32 + c1 * 8;
    const unsigned short* gW0 = wbase + srow0 * 32 + c0 * 8;
    const unsigned short* gW1 = wbase + srow1 * 32 + c1 * 8;
    unsigned short* dH0 = sH + (size_t)(w * 16) * 32;
    unsigned short* dH1 = sH + (size_t)(64 + w * 16) * 32;
    unsigned short* dW0 = sW + (size_t)(w * 16) * 32;
    unsigned short* dW1 = sW + (size_t)(64 + w * 16) * 32;

    int row = lane & 15, q2 = lane >> 4;
    int rw = w & 1, cw = w >> 1;
    int aoff[4], boff[4];
#pragma unroll
    for (int mi = 0; mi < 4; mi++) aoff[mi] = ldsw(rw * 64 + mi * 16 + row, q2);
#pragma unroll
    for (int ni = 0; ni < 4; ni++) boff[ni] = ldsw(cw * 64 + ni * 16 + row, q2);

    v4f acc[4][4];
    v4f zero = {0.f, 0.f, 0.f, 0.f};
#pragma unroll
    for (int mi = 0; mi < 4; mi++)
#pragma unroll
        for (int ni = 0; ni < 4; ni++) acc[mi][ni] = zero;

#define STAGE_D(b, kt) do {                                         \
        gload16(gH0 + (size_t)(kt) * 4096, dH0 + (b) * 4096);       \
        gload16(gH1 + (size_t)(kt) * 4096, dH1 + (b) * 4096);       \
        gload16(gW0 + (size_t)(kt) * 4096, dW0 + (b) * 4096);       \
        gload16(gW1 + (size_t)(kt) * 4096, dW1 + (b) * 4096);       \
    } while (0)

    STAGE_D(0, 0);
    __syncthreads();

#pragma unroll 1
    for (int kt = 0; kt < 16; kt++) {
        int buf = kt & 1;
        if (kt < 15) STAGE_D(buf ^ 1, kt + 1);
        const unsigned short* bH = sH + buf * 4096;
        const unsigned short* bW = sW + buf * 4096;
        v8h a[4], b[4];
#pragma unroll
        for (int mi = 0; mi < 4; mi++) a[mi] = *(const v8h*)&bH[aoff[mi]];
#pragma unroll
        for (int ni = 0; ni < 4; ni++) b[ni] = *(const v8h*)&bW[boff[ni]];
#pragma unroll
        for (int mi = 0; mi < 4; mi++)
#pragma unroll
            for (int ni = 0; ni < 4; ni++)
                acc[mi][ni] = __builtin_amdgcn_mfma_f32_16x16x32_f16(a[mi], b[ni], acc[mi][ni], 0, 0, 0);
        __syncthreads();
    }
#undef STAGE_D

#pragma unroll
    for (int mi = 0; mi < 4; mi++)
#pragma unroll
        for (int ni = 0; ni < 4; ni++) {
            int col = db * 128 + cw * 64 + ni * 16 + row;
#pragma unroll
            for (int i = 0; i < 4; i++) {
                int rl = rw * 64 + mi * 16 + q2 * 4 + i;
                int pos = mt * 128 + rl;
                if (pos < count) {
                    int p = sPair[rl];
                    part[(size_t)p * DIM + col] =
                        __builtin_bit_cast(unsigned short, (_Float16)acc[mi][ni][i]);
                }
            }
        }
}

// ---------------------------------------------------------------- combine ----
__global__ __launch_bounds__(256) void combine_kernel(
    const unsigned short* __restrict__ part, const float* __restrict__ tokW,
    float* __restrict__ out)
{
    int gid = blockIdx.x * 256 + threadIdx.x;
    int t = gid >> 8;
    int c = (gid & 255) * 4;
    float4 r = {0.f, 0.f, 0.f, 0.f};
#pragma unroll
    for (int k = 0; k < TOPK; k++) {
        float wk = tokW[t * TOPK + k];
        union { uint2 u; _Float16 h[4]; } cv;
        cv.u = *(const uint2*)(part + ((size_t)(t * TOPK + k)) * DIM + c);
        r.x += wk * (float)cv.h[0];
        r.y += wk * (float)cv.h[1];
        r.z += wk * (float)cv.h[2];
        r.w += wk * (float)cv.h[3];
    }
    *(float4*)(out + (size_t)t * DIM + c) = r;
}

// ------------------------------------------------------------------- host ----
extern "C" void kernel_launch(void* const* d_in, const int* in_sizes, int n_in,
                              void* d_out, int out_size, void* d_ws, size_t ws_size,
                              hipStream_t stream)
{
    const float* x  = (const float*)d_in[0];
    const float* Wr = (const float*)d_in[1];
    const float* Wg = (const float*)d_in[2];
    const float* Wu = (const float*)d_in[3];
    const float* Wd = (const float*)d_in[4];
    float* out = (float*)d_out;
    char* ws = (char*)d_ws;

    size_t off = 0;
    int* tokIdx = (int*)(ws + off);   off += (size_t)NPAIR * 4;
    float* tokW = (float*)(ws + off); off += (size_t)NPAIR * 4;
    int* cnt    = (int*)(ws + off);   off += 256;
    int* bpair  = (int*)(ws + off);   off += (size_t)NE * CAP * 4;
    unsigned short* xb   = (unsigned short*)(ws + off); off += (size_t)N_TOK * DIM * 2;
    unsigned short* Wg_t = (unsigned short*)(ws + off); off += (size_t)NE * DIM * NF * 2;
    unsigned short* Wu_t = (unsigned short*)(ws + off); off += (size_t)NE * DIM * NF * 2;
    unsigned short* Wd_t = (unsigned short*)(ws + off); off += (size_t)NE * DIM * NF * 2;
    unsigned short* h_t  = (unsigned short*)(ws + off); off += (size_t)MAXTILES * 16 * 4096 * 2;
    unsigned short* part = (unsigned short*)(ws + off); off += (size_t)NPAIR * DIM * 2;

    // router (1024 blocks) + prep of Wg/Wu (4096 blocks), concurrent
    router_prep_kernel<<<RP_ROUTER + RP_PREP, 256, 0, stream>>>(
        x, Wr, Wg, Wu, tokIdx, tokW, xb, Wg_t, Wu_t);
    bin_kernel<<<NE, 256, 0, stream>>>(tokIdx, cnt, bpair);
    // gate_up GEMM (1152, XCD-swizzled) + prep of Wd (2048), concurrent
    ffn_gate_up_kernel<<<GU_BLOCKS + PREPD_BLOCKS, 256, 0, stream>>>(
        xb, Wg_t, Wu_t, cnt, bpair, h_t, Wd, Wd_t);
    ffn_down_kernel<<<DN_BLOCKS, 256, 0, stream>>>(
        h_t, Wd_t, cnt, bpair, part);
    combine_kernel<<<(N_TOK * DIM) / (256 * 4), 256, 0, stream>>>(part, tokW, out);
}